// Round 10
// baseline (223.251 us; speedup 1.0000x reference)
//
#include <hip/hip_runtime.h>

// TinyMLP (2 -> 32 -> 32 -> 1, sigmoid) analytic input-gradient, fused, MFMA-based.
// R10: R9 (zero-LDS, zero-barrier, permlane-pivot body) + DISTANCE-1 REGISTER
// PREFETCH of y1,y2,x1,x2 (4 loop-carried regs).
// Evidence: R9 wall/tile 2096cy = busy 1440 (VALU 1210 + MFMA 230) + idle 656;
// the idle matches the exposed latency of the top-of-body y/x loads consumed
// immediately (convoy in every wave). With zero barriers the prefetch has a
// full-body (~1400cy) window. Spill budget: cap 84 (6 waves/SIMD): reported
// VGPR 40 + ~32 accum + 4 prefetch = ~76 <= 84 (R8's spill was 72 > cap 64).
// Spill tell to check: FETCH/WRITE balloon + VGPR_Count drop.
//
// Pivot-by-swap (verified-by-run R9): lane n / n+32 jointly hold all 32 rows of
// batch col n; v_permlane32_swap_b32 d,s -> d'=[d.lo|s.lo], s'=[d.hi|s.hi].
// swap(P[2t], P[2t+2]) yields exactly B-frag ints (2t,2t+2) for both lane halves.
//   MFMA z1  (x1): -log2e*Z1^T = A_z1 @ Y^T    (y hi/lo bf16 split, b1 in K-slots 6,7)
//   MFMA z2  (x2): -log2e*Z2^T = W2s @ H1^T    (K=32; acc init = -log2e*b2)
//   MFMA dh1 (x2): dH1^T = (W2*W3) @ dZ2^T     (W3 folded into weights at init)
//   MFMA dy  (x2): dY^T  = W1 @ dZ1^T          (g1,g2 = regs 0,1 of lanes 0-31)
//
// Layouts (32x32x16 bf16; verified-by-run R5/R9):
//   A-frag: lane holds A[row=lane&31][k=(lane>>5)*8+j]
//   B-frag: lane holds B[k=(lane>>5)*8+j][n=lane&31]
//   C/D:    lane holds D[row=(reg&3)+8*(reg>>2)+4*(lane>>5)][col=lane&31]

#define H 32
#define NLOG2E (-1.4426950408889634f)

typedef __attribute__((ext_vector_type(8))) short bf16x8;
typedef __attribute__((ext_vector_type(16))) float f32x16;
typedef __attribute__((ext_vector_type(4))) float f32x4;
typedef __attribute__((ext_vector_type(2))) float f32x2;
typedef __attribute__((ext_vector_type(2))) __bf16 bfx2;

#define MFMA32 __builtin_amdgcn_mfma_f32_32x32x16_bf16

__device__ __forceinline__ int cvt_pk_bf16(float a, float b) {
    f32x2 f; f[0] = a; f[1] = b;
    bfx2 r = __builtin_convertvector(f, bfx2);   // v_cvt_pk_bf16_f32 (RNE)
    return __builtin_bit_cast(int, r);
}
__device__ __forceinline__ float pklo(int p) {               // low bf16 of packed pair
    unsigned u = (unsigned)p << 16; return __builtin_bit_cast(float, u);
}
__device__ __forceinline__ float pkhi(int p) {               // high bf16 of packed pair
    unsigned u = (unsigned)p & 0xFFFF0000u; return __builtin_bit_cast(float, u);
}

// d.hi <-> s.lo (gfx950): after the asm, d = [d.lo|s.lo], s = [d.hi|s.hi].
__device__ __forceinline__ void plane32_swap(int &d, int &s) {
    asm volatile("v_permlane32_swap_b32 %0, %1" : "+v"(d), "+v"(s));
}

// Batched reciprocal: one v_rcp_f32 for four positive values (a_i = 1+e, e <= ~2^8:
// product <= ~3.4e8, no overflow; error ~few ulp, far below bf16 rounding).
__device__ __forceinline__ f32x4 rcp4(const f32x4 a) {
    float m01 = a[0] * a[1], m23 = a[2] * a[3];
    float r   = __builtin_amdgcn_rcpf(m01 * m23);
    float r01 = r * m23, r23 = r * m01;
    f32x4 s; s[0] = a[1] * r01; s[1] = a[0] * r01; s[2] = a[3] * r23; s[3] = a[2] * r23;
    return s;
}

__global__ __launch_bounds__(256, 6) void tinymlp_mfma_kernel(
    const float* __restrict__ x1, const float* __restrict__ x2,
    const float* __restrict__ y1, const float* __restrict__ y2,
    const float* __restrict__ W1, const float* __restrict__ b1,
    const float* __restrict__ W2, const float* __restrict__ b2,
    const float* __restrict__ W3,
    float4* __restrict__ out, int ntiles)
{
    const int tid  = threadIdx.x;
    const int lane = tid & 63;
    const int n    = lane & 31;   // batch column (and weight row for A-frags)
    const int q5   = lane >> 5;   // k-half / h-half selector

    union U4 { int i[4]; bf16x8 v; };
    U4 A_z1, A_z2a, A_z2b, A_dh1a, A_dh1b, A_dya, A_dyb;

    #pragma unroll
    for (int t = 0; t < 4; ++t) {
        const int j0 = 8 * q5 + 2 * t;
        const int j1 = j0 + 1;
        // z2: A[h2=n][k=h1], forward scale folded
        A_z2a.i[t] = cvt_pk_bf16(NLOG2E * W2[j0 * H + n],        NLOG2E * W2[j1 * H + n]);
        A_z2b.i[t] = cvt_pk_bf16(NLOG2E * W2[(16 + j0) * H + n], NLOG2E * W2[(16 + j1) * H + n]);
        // dh1: A[h1=n][k=h2], W3 pre-folded
        A_dh1a.i[t] = cvt_pk_bf16(W2[n * H + j0] * W3[j0],           W2[n * H + j1] * W3[j1]);
        A_dh1b.i[t] = cvt_pk_bf16(W2[n * H + 16 + j0] * W3[16 + j0], W2[n * H + 16 + j1] * W3[16 + j1]);
        // dy: A[c=n][k=h1], rows >= 2 zero
        A_dya.i[t] = (n < 2) ? cvt_pk_bf16(W1[n * H + j0],      W1[n * H + j1])      : 0;
        A_dyb.i[t] = (n < 2) ? cvt_pk_bf16(W1[n * H + 16 + j0], W1[n * H + 16 + j1]) : 0;
    }

    // z1 A-frag: k-slots (q5==0 half): {whi0,whi1, wlo0,wlo1, whi0,whi1, b1hi,b1lo}
    // pairing with B = {y1hi,y2hi, y1hi,y2hi, y1lo,y2lo, 1,1}; q5==1 half all zero.
    A_z1.i[0] = A_z1.i[1] = A_z1.i[2] = A_z1.i[3] = 0;
    if (q5 == 0) {
        const float wa = NLOG2E * W1[n];
        const float wb = NLOG2E * W1[H + n];
        const float bv = NLOG2E * b1[n];
        const int hi  = cvt_pk_bf16(wa, wb);
        const int lo  = cvt_pk_bf16(wa - pklo(hi), wb - pkhi(hi));
        const int bh  = cvt_pk_bf16(bv, 0.f);
        const int bhl = cvt_pk_bf16(bv, bv - pklo(bh));
        A_z1.i[0] = hi; A_z1.i[1] = lo; A_z1.i[2] = hi; A_z1.i[3] = bhl;
    }

    // acc init for z2: -log2e*b2 at rows h2 = (r&3)+8*(r>>2)+4*q5
    f32x16 b2C;
    #pragma unroll
    for (int t = 0; t < 4; ++t) {
        const float4 bt = *(const float4*)&b2[8 * t + 4 * q5];
        b2C[4 * t + 0] = NLOG2E * bt.x; b2C[4 * t + 1] = NLOG2E * bt.y;
        b2C[4 * t + 2] = NLOG2E * bt.z; b2C[4 * t + 3] = NLOG2E * bt.w;
    }

    f32x16 zf16;
    #pragma unroll
    for (int r = 0; r < 16; ++r) zf16[r] = 0.f;

    const int gwave  = (blockIdx.x * blockDim.x + tid) >> 6;
    const int nwaves = (gridDim.x * blockDim.x) >> 6;
    unsigned idx = (unsigned)gwave * 32 + (unsigned)n;   // lanes 0-31 load/store
    const unsigned step = (unsigned)nwaves * 32;

    // ---- prologue: first tile's y/x in registers ----
    float cy1 = 0.f, cy2 = 0.f, cx1 = 0.f, cx2 = 0.f;
    if (lane < 32) {
        cy1 = y1[idx]; cy2 = y2[idx];
        cx1 = x1[idx]; cx2 = x2[idx];
    }

    for (int tt = gwave; tt < ntiles; tt += nwaves) {
        // ---- distance-1 prefetch: next tile's y/x; first use is a full body away ----
        const unsigned idxn = (tt + nwaves < ntiles) ? idx + step : idx;  // clamped reload
        float ny1 = 0.f, ny2 = 0.f, nx1 = 0.f, nx2 = 0.f;
        if (lane < 32) {
            ny1 = y1[idxn]; ny2 = y2[idxn];
            nx1 = x1[idxn]; nx2 = x2[idxn];
        }

        // ---- B-frag for z1: y hi/lo split; upper-half A is zero so uY there is don't-care
        U4 uY;
        const int pkHI = cvt_pk_bf16(cy1, cy2);
        const int pkLO = cvt_pk_bf16(cy1 - pklo(pkHI), cy2 - pkhi(pkHI));
        uY.i[0] = pkHI; uY.i[1] = pkHI; uY.i[2] = pkLO;
        uY.i[3] = 0x3F803F80;   // (1.0,1.0) bias slots

        // ---- z1^T (scaled): one 32x32x16 MFMA ----
        const f32x16 acc = MFMA32(A_z1.v, uY.v, zf16, 0, 0, 0);

        // ---- sigmoid layer 1: 16 exp2 + 4 rcp; pack s -> P (kept for h1d) ----
        int P[8];
        #pragma unroll
        for (int t = 0; t < 4; ++t) {
            f32x4 e;
            #pragma unroll
            for (int r = 0; r < 4; ++r) e[r] = __builtin_amdgcn_exp2f(acc[4 * t + r]);
            e += 1.0f;
            const f32x4 s = rcp4(e);
            P[2 * t]     = cvt_pk_bf16(s[0], s[1]);
            P[2 * t + 1] = cvt_pk_bf16(s[2], s[3]);
        }

        // ---- pivot h1 C->B via permlane32_swap (copies preserve P for h1d) ----
        U4 B1f, B2f;
        {
            int a0 = P[0], a2 = P[2]; plane32_swap(a0, a2);
            int a1 = P[1], a3 = P[3]; plane32_swap(a1, a3);
            B1f.i[0] = a0; B1f.i[1] = a1; B1f.i[2] = a2; B1f.i[3] = a3;
            int b0 = P[4], b2i = P[6]; plane32_swap(b0, b2i);
            int b1i = P[5], b3 = P[7]; plane32_swap(b1i, b3);
            B2f.i[0] = b0; B2f.i[1] = b1i; B2f.i[2] = b2i; B2f.i[3] = b3;
        }

        // ---- z2^T (scaled, b2 in acc init): K=32 via 2 chained MFMAs ----
        f32x16 zz = MFMA32(A_z2a.v, B1f.v, b2C, 0, 0, 0);
        zz = MFMA32(A_z2b.v, B2f.v, zz, 0, 0, 0);

        // ---- dz2 = s2*(1-s2) (W3 folded into dh1 A); pack Q ----
        int Q[8];
        #pragma unroll
        for (int t = 0; t < 4; ++t) {
            f32x4 e;
            #pragma unroll
            for (int r = 0; r < 4; ++r) e[r] = __builtin_amdgcn_exp2f(zz[4 * t + r]);
            e += 1.0f;
            const f32x4 s = rcp4(e);
            f32x2 sv;
            sv[0] = s[0]; sv[1] = s[1];
            sv = __builtin_elementwise_fma(-sv, sv, sv);
            Q[2 * t] = cvt_pk_bf16(sv[0], sv[1]);
            sv[0] = s[2]; sv[1] = s[3];
            sv = __builtin_elementwise_fma(-sv, sv, sv);
            Q[2 * t + 1] = cvt_pk_bf16(sv[0], sv[1]);
        }

        // ---- pivot dz2 C->B via swaps (Q dead after; swap in place) ----
        U4 D1f, D2f;
        plane32_swap(Q[0], Q[2]);
        plane32_swap(Q[1], Q[3]);
        D1f.i[0] = Q[0]; D1f.i[1] = Q[1]; D1f.i[2] = Q[2]; D1f.i[3] = Q[3];
        plane32_swap(Q[4], Q[6]);
        plane32_swap(Q[5], Q[7]);
        D2f.i[0] = Q[4]; D2f.i[1] = Q[5]; D2f.i[2] = Q[6]; D2f.i[3] = Q[7];

        // ---- dH1^T = (W2*W3) @ dZ2^T ----
        f32x16 dh = MFMA32(A_dh1a.v, D1f.v, zf16, 0, 0, 0);
        dh = MFMA32(A_dh1b.v, D2f.v, dh, 0, 0, 0);

        // ---- dz1 = dH1 * h1d (h1d recomputed from packed bf16 s); pack G ----
        int G[8];
        #pragma unroll
        for (int t = 0; t < 4; ++t) {
            f32x2 sv, gg;
            sv[0] = pklo(P[2 * t]); sv[1] = pkhi(P[2 * t]);
            sv = __builtin_elementwise_fma(-sv, sv, sv);
            gg[0] = dh[4 * t]; gg[1] = dh[4 * t + 1]; gg *= sv;
            G[2 * t] = cvt_pk_bf16(gg[0], gg[1]);
            sv[0] = pklo(P[2 * t + 1]); sv[1] = pkhi(P[2 * t + 1]);
            sv = __builtin_elementwise_fma(-sv, sv, sv);
            gg[0] = dh[4 * t + 2]; gg[1] = dh[4 * t + 3]; gg *= sv;
            G[2 * t + 1] = cvt_pk_bf16(gg[0], gg[1]);
        }

        // ---- pivot dz1 C->B via swaps (G dead after) ----
        U4 E1f, E2f;
        plane32_swap(G[0], G[2]);
        plane32_swap(G[1], G[3]);
        E1f.i[0] = G[0]; E1f.i[1] = G[1]; E1f.i[2] = G[2]; E1f.i[3] = G[3];
        plane32_swap(G[4], G[6]);
        plane32_swap(G[5], G[7]);
        E2f.i[0] = G[4]; E2f.i[1] = G[5]; E2f.i[2] = G[6]; E2f.i[3] = G[7];

        // ---- dY^T = W1 @ dZ1^T: lanes 0-31 hold g1=reg0, g2=reg1 ----
        f32x16 ay = MFMA32(A_dya.v, E1f.v, zf16, 0, 0, 0);
        ay = MFMA32(A_dyb.v, E2f.v, ay, 0, 0, 0);

        if (lane < 32) {
            float4 o;
            o.x = cx1 + ay[0];
            o.y = cx2 + ay[1];
            o.z = cy1;
            o.w = cy2;
            out[idx] = o;
        }

        // ---- rotate prefetched values ----
        cy1 = ny1; cy2 = ny2; cx1 = nx1; cx2 = nx2;
        idx = idxn;
    }
}

extern "C" void kernel_launch(void* const* d_in, const int* in_sizes, int n_in,
                              void* d_out, int out_size, void* d_ws, size_t ws_size,
                              hipStream_t stream) {
    const float* x1 = (const float*)d_in[0];
    const float* x2 = (const float*)d_in[1];
    const float* y1 = (const float*)d_in[2];
    const float* y2 = (const float*)d_in[3];
    const float* W1 = (const float*)d_in[4];
    const float* b1 = (const float*)d_in[5];
    const float* W2 = (const float*)d_in[6];
    const float* b2 = (const float*)d_in[7];
    const float* W3 = (const float*)d_in[8];
    // d_in[9] = b3: drops out of the input-gradient — unused.

    const int n = in_sizes[0];
    const int ntiles = n / 32;       // B = 4194304 -> 131072 tiles of 32
    const int block = 256;           // 4 waves
    const int grid = 1536;           // 6 blocks/CU (cap 84 regs incl. accums; ~76 used)
    tinymlp_mfma_kernel<<<grid, block, 0, stream>>>(
        x1, x2, y1, y2, W1, b1, W2, b2, W3, (float4*)d_out, ntiles);
}

// Round 11
// 210.300 us; speedup vs baseline: 1.0616x; 1.0616x over previous
//
#include <hip/hip_runtime.h>

// TinyMLP (2 -> 32 -> 32 -> 1, sigmoid) analytic input-gradient, fused, MFMA-based.
// R11: R9 (zero-barrier permlane-pivot body) + y-PREFETCH THROUGH LDS via
// global_load_lds (zero VGPR transit — R10 proved any loop-carried VGPR state
// spills: VGPR pinned 40, FETCH+11MB/WRITE+20MB scratch traffic, dur +17us).
// Evidence: R9 wall/tile 2096cy = busy 1440 + idle 656; idle == exposed latency of
// the y-loads consumed immediately at the head of each chain (x is consumed only at
// the store -> already hidden). Mechanism: per wave, 2-buffer LDS strip; top of body
// reads current y via ds_read (~120cy), then issues glds for next tile into the
// other buffer (full ~1400cy body of cover).
// vmcnt discipline (in-order retirement): issue order pinned [glds,glds | x,x,store]
// by sched_barrier(0) after the glds pair -> s_waitcnt vmcnt(3) at loop-back
// guarantees the 2 glds retired without waiting on the younger store. Prologue
// waits vmcnt(0) once. sched_barrier(0) after every asm waitcnt (hoist guard).
//
// Pivot-by-swap (verified-by-run R9): lane n / n+32 jointly hold all 32 rows of
// batch col n; v_permlane32_swap_b32 d,s -> d'=[d.lo|s.lo], s'=[d.hi|s.hi].
//   MFMA z1  (x1): -log2e*Z1^T = A_z1 @ Y^T    (y hi/lo bf16 split, b1 in K-slots 6,7)
//   MFMA z2  (x2): -log2e*Z2^T = W2s @ H1^T    (K=32; acc init = -log2e*b2)
//   MFMA dh1 (x2): dH1^T = (W2*W3) @ dZ2^T     (W3 folded into weights at init)
//   MFMA dy  (x2): dY^T  = W1 @ dZ1^T          (g1,g2 = regs 0,1 of lanes 0-31)
//
// Layouts (32x32x16 bf16; verified-by-run R5/R9):
//   A-frag: lane holds A[row=lane&31][k=(lane>>5)*8+j]
//   B-frag: lane holds B[k=(lane>>5)*8+j][n=lane&31]
//   C/D:    lane holds D[row=(reg&3)+8*(reg>>2)+4*(lane>>5)][col=lane&31]

#define H 32
#define NLOG2E (-1.4426950408889634f)

typedef __attribute__((ext_vector_type(8))) short bf16x8;
typedef __attribute__((ext_vector_type(16))) float f32x16;
typedef __attribute__((ext_vector_type(4))) float f32x4;
typedef __attribute__((ext_vector_type(2))) float f32x2;
typedef __attribute__((ext_vector_type(2))) __bf16 bfx2;

#define MFMA32 __builtin_amdgcn_mfma_f32_32x32x16_bf16

__device__ __forceinline__ int cvt_pk_bf16(float a, float b) {
    f32x2 f; f[0] = a; f[1] = b;
    bfx2 r = __builtin_convertvector(f, bfx2);   // v_cvt_pk_bf16_f32 (RNE)
    return __builtin_bit_cast(int, r);
}
__device__ __forceinline__ float pklo(int p) {               // low bf16 of packed pair
    unsigned u = (unsigned)p << 16; return __builtin_bit_cast(float, u);
}
__device__ __forceinline__ float pkhi(int p) {               // high bf16 of packed pair
    unsigned u = (unsigned)p & 0xFFFF0000u; return __builtin_bit_cast(float, u);
}

// d.hi <-> s.lo (gfx950): after the asm, d = [d.lo|s.lo], s = [d.hi|s.hi].
__device__ __forceinline__ void plane32_swap(int &d, int &s) {
    asm volatile("v_permlane32_swap_b32 %0, %1" : "+v"(d), "+v"(s));
}

// async global->LDS, 4B/lane, dest = uniform base + lane*4 (active lanes only)
__device__ __forceinline__ void glds4(const float* g, float* l) {
    __builtin_amdgcn_global_load_lds(
        (const __attribute__((address_space(1))) void*)g,
        (__attribute__((address_space(3))) void*)l, 4, 0, 0);
}

// Batched reciprocal: one v_rcp_f32 for four positive values (a_i = 1+e, e <= ~2^8:
// product <= ~3.4e8, no overflow; error ~few ulp, far below bf16 rounding).
__device__ __forceinline__ f32x4 rcp4(const f32x4 a) {
    float m01 = a[0] * a[1], m23 = a[2] * a[3];
    float r   = __builtin_amdgcn_rcpf(m01 * m23);
    float r01 = r * m23, r23 = r * m01;
    f32x4 s; s[0] = a[1] * r01; s[1] = a[0] * r01; s[2] = a[3] * r23; s[3] = a[2] * r23;
    return s;
}

__global__ __launch_bounds__(256, 6) void tinymlp_mfma_kernel(
    const float* __restrict__ x1, const float* __restrict__ x2,
    const float* __restrict__ y1, const float* __restrict__ y2,
    const float* __restrict__ W1, const float* __restrict__ b1,
    const float* __restrict__ W2, const float* __restrict__ b2,
    const float* __restrict__ W3,
    float4* __restrict__ out, int ntiles)
{
    // y-prefetch strip: [wave][buf][arr: y1,y2][lane], 2 KB/block
    __shared__ float pl[4][2][2][32];

    const int tid  = threadIdx.x;
    const int w    = tid >> 6;
    const int lane = tid & 63;
    const int n    = lane & 31;   // batch column (and weight row for A-frags)
    const int q5   = lane >> 5;   // k-half / h-half selector

    union U4 { int i[4]; bf16x8 v; };
    U4 A_z1, A_z2a, A_z2b, A_dh1a, A_dh1b, A_dya, A_dyb;

    #pragma unroll
    for (int t = 0; t < 4; ++t) {
        const int j0 = 8 * q5 + 2 * t;
        const int j1 = j0 + 1;
        // z2: A[h2=n][k=h1], forward scale folded
        A_z2a.i[t] = cvt_pk_bf16(NLOG2E * W2[j0 * H + n],        NLOG2E * W2[j1 * H + n]);
        A_z2b.i[t] = cvt_pk_bf16(NLOG2E * W2[(16 + j0) * H + n], NLOG2E * W2[(16 + j1) * H + n]);
        // dh1: A[h1=n][k=h2], W3 pre-folded
        A_dh1a.i[t] = cvt_pk_bf16(W2[n * H + j0] * W3[j0],           W2[n * H + j1] * W3[j1]);
        A_dh1b.i[t] = cvt_pk_bf16(W2[n * H + 16 + j0] * W3[16 + j0], W2[n * H + 16 + j1] * W3[16 + j1]);
        // dy: A[c=n][k=h1], rows >= 2 zero
        A_dya.i[t] = (n < 2) ? cvt_pk_bf16(W1[n * H + j0],      W1[n * H + j1])      : 0;
        A_dyb.i[t] = (n < 2) ? cvt_pk_bf16(W1[n * H + 16 + j0], W1[n * H + 16 + j1]) : 0;
    }

    // z1 A-frag: k-slots (q5==0 half): {whi0,whi1, wlo0,wlo1, whi0,whi1, b1hi,b1lo}
    // pairing with B = {y1hi,y2hi, y1hi,y2hi, y1lo,y2lo, 1,1}; q5==1 half all zero.
    A_z1.i[0] = A_z1.i[1] = A_z1.i[2] = A_z1.i[3] = 0;
    if (q5 == 0) {
        const float wa = NLOG2E * W1[n];
        const float wb = NLOG2E * W1[H + n];
        const float bv = NLOG2E * b1[n];
        const int hi  = cvt_pk_bf16(wa, wb);
        const int lo  = cvt_pk_bf16(wa - pklo(hi), wb - pkhi(hi));
        const int bh  = cvt_pk_bf16(bv, 0.f);
        const int bhl = cvt_pk_bf16(bv, bv - pklo(bh));
        A_z1.i[0] = hi; A_z1.i[1] = lo; A_z1.i[2] = hi; A_z1.i[3] = bhl;
    }

    // acc init for z2: -log2e*b2 at rows h2 = (r&3)+8*(r>>2)+4*q5
    f32x16 b2C;
    #pragma unroll
    for (int t = 0; t < 4; ++t) {
        const float4 bt = *(const float4*)&b2[8 * t + 4 * q5];
        b2C[4 * t + 0] = NLOG2E * bt.x; b2C[4 * t + 1] = NLOG2E * bt.y;
        b2C[4 * t + 2] = NLOG2E * bt.z; b2C[4 * t + 3] = NLOG2E * bt.w;
    }

    f32x16 zf16;
    #pragma unroll
    for (int r = 0; r < 16; ++r) zf16[r] = 0.f;

    const int gwave  = (blockIdx.x * blockDim.x + tid) >> 6;
    const int nwaves = (gridDim.x * blockDim.x) >> 6;
    unsigned idx = (unsigned)gwave * 32 + (unsigned)n;   // lanes 0-31 load/store
    const unsigned step = (unsigned)nwaves * 32;

    // ---- prologue: first tile's y into buf 0; drain once ----
    int cb = 0;
    if (lane < 32) {
        glds4(y1 + idx, &pl[w][0][0][0]);
        glds4(y2 + idx, &pl[w][0][1][0]);
    }
    asm volatile("s_waitcnt vmcnt(0)" ::: "memory");
    __builtin_amdgcn_sched_barrier(0);

    for (int tt = gwave; tt < ntiles; tt += nwaves) {
        const unsigned idxn = (tt + nwaves < ntiles) ? idx + step : idx;  // clamped

        // ---- current y from LDS; issue next tile's glds; x direct (hidden) ----
        float cy1 = 0.f, cy2 = 0.f, cx1 = 0.f, cx2 = 0.f;
        if (lane < 32) {
            cy1 = pl[w][cb][0][n];
            cy2 = pl[w][cb][1][n];
            glds4(y1 + idxn, &pl[w][cb ^ 1][0][0]);
            glds4(y2 + idxn, &pl[w][cb ^ 1][1][0]);
        }
        // pin vmem issue order: [glds, glds | x, x, store] for the vmcnt(3) below
        __builtin_amdgcn_sched_barrier(0);
        if (lane < 32) {
            cx1 = x1[idx]; cx2 = x2[idx];
        }

        // ---- B-frag for z1: y hi/lo split; upper-half A is zero (don't-care B) ----
        U4 uY;
        const int pkHI = cvt_pk_bf16(cy1, cy2);
        const int pkLO = cvt_pk_bf16(cy1 - pklo(pkHI), cy2 - pkhi(pkHI));
        uY.i[0] = pkHI; uY.i[1] = pkHI; uY.i[2] = pkLO;
        uY.i[3] = 0x3F803F80;   // (1.0,1.0) bias slots

        // ---- z1^T (scaled): one 32x32x16 MFMA ----
        const f32x16 acc = MFMA32(A_z1.v, uY.v, zf16, 0, 0, 0);

        // ---- sigmoid layer 1: 16 exp2 + 4 rcp; pack s -> P (kept for h1d) ----
        int P[8];
        #pragma unroll
        for (int t = 0; t < 4; ++t) {
            f32x4 e;
            #pragma unroll
            for (int r = 0; r < 4; ++r) e[r] = __builtin_amdgcn_exp2f(acc[4 * t + r]);
            e += 1.0f;
            const f32x4 s = rcp4(e);
            P[2 * t]     = cvt_pk_bf16(s[0], s[1]);
            P[2 * t + 1] = cvt_pk_bf16(s[2], s[3]);
        }

        // ---- pivot h1 C->B via permlane32_swap (copies preserve P for h1d) ----
        U4 B1f, B2f;
        {
            int a0 = P[0], a2 = P[2]; plane32_swap(a0, a2);
            int a1 = P[1], a3 = P[3]; plane32_swap(a1, a3);
            B1f.i[0] = a0; B1f.i[1] = a1; B1f.i[2] = a2; B1f.i[3] = a3;
            int b0 = P[4], b2i = P[6]; plane32_swap(b0, b2i);
            int b1i = P[5], b3 = P[7]; plane32_swap(b1i, b3);
            B2f.i[0] = b0; B2f.i[1] = b1i; B2f.i[2] = b2i; B2f.i[3] = b3;
        }

        // ---- z2^T (scaled, b2 in acc init): K=32 via 2 chained MFMAs ----
        f32x16 zz = MFMA32(A_z2a.v, B1f.v, b2C, 0, 0, 0);
        zz = MFMA32(A_z2b.v, B2f.v, zz, 0, 0, 0);

        // ---- dz2 = s2*(1-s2) (W3 folded into dh1 A); pack Q ----
        int Q[8];
        #pragma unroll
        for (int t = 0; t < 4; ++t) {
            f32x4 e;
            #pragma unroll
            for (int r = 0; r < 4; ++r) e[r] = __builtin_amdgcn_exp2f(zz[4 * t + r]);
            e += 1.0f;
            const f32x4 s = rcp4(e);
            f32x2 sv;
            sv[0] = s[0]; sv[1] = s[1];
            sv = __builtin_elementwise_fma(-sv, sv, sv);
            Q[2 * t] = cvt_pk_bf16(sv[0], sv[1]);
            sv[0] = s[2]; sv[1] = s[3];
            sv = __builtin_elementwise_fma(-sv, sv, sv);
            Q[2 * t + 1] = cvt_pk_bf16(sv[0], sv[1]);
        }

        // ---- pivot dz2 C->B via swaps (Q dead after; swap in place) ----
        U4 D1f, D2f;
        plane32_swap(Q[0], Q[2]);
        plane32_swap(Q[1], Q[3]);
        D1f.i[0] = Q[0]; D1f.i[1] = Q[1]; D1f.i[2] = Q[2]; D1f.i[3] = Q[3];
        plane32_swap(Q[4], Q[6]);
        plane32_swap(Q[5], Q[7]);
        D2f.i[0] = Q[4]; D2f.i[1] = Q[5]; D2f.i[2] = Q[6]; D2f.i[3] = Q[7];

        // ---- dH1^T = (W2*W3) @ dZ2^T ----
        f32x16 dh = MFMA32(A_dh1a.v, D1f.v, zf16, 0, 0, 0);
        dh = MFMA32(A_dh1b.v, D2f.v, dh, 0, 0, 0);

        // ---- dz1 = dH1 * h1d (h1d recomputed from packed bf16 s); pack G ----
        int G[8];
        #pragma unroll
        for (int t = 0; t < 4; ++t) {
            f32x2 sv, gg;
            sv[0] = pklo(P[2 * t]); sv[1] = pkhi(P[2 * t]);
            sv = __builtin_elementwise_fma(-sv, sv, sv);
            gg[0] = dh[4 * t]; gg[1] = dh[4 * t + 1]; gg *= sv;
            G[2 * t] = cvt_pk_bf16(gg[0], gg[1]);
            sv[0] = pklo(P[2 * t + 1]); sv[1] = pkhi(P[2 * t + 1]);
            sv = __builtin_elementwise_fma(-sv, sv, sv);
            gg[0] = dh[4 * t + 2]; gg[1] = dh[4 * t + 3]; gg *= sv;
            G[2 * t + 1] = cvt_pk_bf16(gg[0], gg[1]);
        }

        // ---- pivot dz1 C->B via swaps (G dead after) ----
        U4 E1f, E2f;
        plane32_swap(G[0], G[2]);
        plane32_swap(G[1], G[3]);
        E1f.i[0] = G[0]; E1f.i[1] = G[1]; E1f.i[2] = G[2]; E1f.i[3] = G[3];
        plane32_swap(G[4], G[6]);
        plane32_swap(G[5], G[7]);
        E2f.i[0] = G[4]; E2f.i[1] = G[5]; E2f.i[2] = G[6]; E2f.i[3] = G[7];

        // ---- dY^T = W1 @ dZ1^T: lanes 0-31 hold g1=reg0, g2=reg1 ----
        f32x16 ay = MFMA32(A_dya.v, E1f.v, zf16, 0, 0, 0);
        ay = MFMA32(A_dyb.v, E2f.v, ay, 0, 0, 0);

        if (lane < 32) {
            float4 o;
            o.x = cx1 + ay[0];
            o.y = cx2 + ay[1];
            o.z = cy1;
            o.w = cy2;
            out[idx] = o;
        }

        cb ^= 1;
        idx = idxn;

        // ---- loop-back: the 2 glds (oldest of this iter's 5 vmem ops) must be
        //      retired before the next ds_read; store may stay outstanding ----
        asm volatile("s_waitcnt vmcnt(3)" ::: "memory");
        __builtin_amdgcn_sched_barrier(0);
    }
}

extern "C" void kernel_launch(void* const* d_in, const int* in_sizes, int n_in,
                              void* d_out, int out_size, void* d_ws, size_t ws_size,
                              hipStream_t stream) {
    const float* x1 = (const float*)d_in[0];
    const float* x2 = (const float*)d_in[1];
    const float* y1 = (const float*)d_in[2];
    const float* y2 = (const float*)d_in[3];
    const float* W1 = (const float*)d_in[4];
    const float* b1 = (const float*)d_in[5];
    const float* W2 = (const float*)d_in[6];
    const float* b2 = (const float*)d_in[7];
    const float* W3 = (const float*)d_in[8];
    // d_in[9] = b3: drops out of the input-gradient — unused.

    const int n = in_sizes[0];
    const int ntiles = n / 32;       // B = 4194304 -> 131072 tiles of 32
    const int block = 256;           // 4 waves
    const int grid = 1536;           // 6 blocks/CU (no-spill cap incl. accums)
    tinymlp_mfma_kernel<<<grid, block, 0, stream>>>(
        x1, x2, y1, y2, W1, b1, W2, b2, W3, (float4*)d_out, ntiles);
}

// Round 12
// 208.604 us; speedup vs baseline: 1.0702x; 1.0081x over previous
//
#include <hip/hip_runtime.h>

// TinyMLP (2 -> 32 -> 32 -> 1, sigmoid) analytic input-gradient, fused, MFMA-based.
// R12: VALU-DEMAND REDUCTION on the R9 structure (zero-LDS, zero-barrier,
// permlane-pivot body; R11's glds prefetch removed — it was +5us).
// Evidence: VALU duty pinned 55-63% across ALL structures (R1/R5/R9/R11) while
// three latency-hiding mechanisms (tile-pairing R2, reg-prefetch R10, LDS-prefetch
// R11) returned null -> kernel is VALU-issue-bound near the chip's practical VALU
// ceiling (m07: even pure v_fma peaks at 65%). Only lever left: fewer VALU cycles.
//   1. rcp8: ONE v_rcp per 8 sigmoid denominators (pk-structured product tree,
//      12 muls + 1 rcp per 8 vs rcp4x2 = 16 muls + 2 rcp). Trans 40 -> 36/tile.
//   2. Explicit f32x2 packed math (v_pk_add/mul/fma) in both sigmoid blocks.
//   3. In-place pivot swaps for dz2/dz1 (cvt_pk written straight into the B-frag
//      union, swap in place) — kills tuple-assembly movs.
// Occupancy held at proven-safe 6 waves/SIMD (true reg need 65-84 incl. MFMA
// accums; cap-64 spills catastrophically — R4/R7/R8/R10).
//
// Pivot-by-swap (verified-by-run R9): lane n / n+32 jointly hold all 32 rows of
// batch col n; v_permlane32_swap_b32 d,s -> d'=[d.lo|s.lo], s'=[d.hi|s.hi].
//   MFMA z1  (x1): -log2e*Z1^T = A_z1 @ Y^T    (y hi/lo bf16 split, b1 in K-slots 6,7)
//   MFMA z2  (x2): -log2e*Z2^T = W2s @ H1^T    (K=32; acc init = -log2e*b2)
//   MFMA dh1 (x2): dH1^T = (W2*W3) @ dZ2^T     (W3 folded into weights at init)
//   MFMA dy  (x2): dY^T  = W1 @ dZ1^T          (g1,g2 = regs 0,1 of lanes 0-31)
//
// Layouts (32x32x16 bf16; verified-by-run R5/R9):
//   A-frag: lane holds A[row=lane&31][k=(lane>>5)*8+j]
//   B-frag: lane holds B[k=(lane>>5)*8+j][n=lane&31]
//   C/D:    lane holds D[row=(reg&3)+8*(reg>>2)+4*(lane>>5)][col=lane&31]

#define H 32
#define NLOG2E (-1.4426950408889634f)

typedef __attribute__((ext_vector_type(8))) short bf16x8;
typedef __attribute__((ext_vector_type(16))) float f32x16;
typedef __attribute__((ext_vector_type(2))) float f32x2;
typedef __attribute__((ext_vector_type(2))) __bf16 bfx2;

#define MFMA32 __builtin_amdgcn_mfma_f32_32x32x16_bf16

__device__ __forceinline__ int cvt_pk_bf16(float a, float b) {
    f32x2 f; f[0] = a; f[1] = b;
    bfx2 r = __builtin_convertvector(f, bfx2);   // v_cvt_pk_bf16_f32 (RNE)
    return __builtin_bit_cast(int, r);
}
__device__ __forceinline__ float pklo(int p) {               // low bf16 of packed pair
    unsigned u = (unsigned)p << 16; return __builtin_bit_cast(float, u);
}
__device__ __forceinline__ float pkhi(int p) {               // high bf16 of packed pair
    unsigned u = (unsigned)p & 0xFFFF0000u; return __builtin_bit_cast(float, u);
}

// d.hi <-> s.lo (gfx950): after the asm, d = [d.lo|s.lo], s = [d.hi|s.hi].
__device__ __forceinline__ void plane32_swap(int &d, int &s) {
    asm volatile("v_permlane32_swap_b32 %0, %1" : "+v"(d), "+v"(s));
}

__global__ __launch_bounds__(256, 6) void tinymlp_mfma_kernel(
    const float* __restrict__ x1, const float* __restrict__ x2,
    const float* __restrict__ y1, const float* __restrict__ y2,
    const float* __restrict__ W1, const float* __restrict__ b1,
    const float* __restrict__ W2, const float* __restrict__ b2,
    const float* __restrict__ W3,
    float4* __restrict__ out, int ntiles)
{
    const int tid  = threadIdx.x;
    const int lane = tid & 63;
    const int n    = lane & 31;   // batch column (and weight row for A-frags)
    const int q5   = lane >> 5;   // k-half / h-half selector

    union U4 { int i[4]; bf16x8 v; };
    U4 A_z1, A_z2a, A_z2b, A_dh1a, A_dh1b, A_dya, A_dyb;

    #pragma unroll
    for (int t = 0; t < 4; ++t) {
        const int j0 = 8 * q5 + 2 * t;
        const int j1 = j0 + 1;
        // z2: A[h2=n][k=h1], forward scale folded
        A_z2a.i[t] = cvt_pk_bf16(NLOG2E * W2[j0 * H + n],        NLOG2E * W2[j1 * H + n]);
        A_z2b.i[t] = cvt_pk_bf16(NLOG2E * W2[(16 + j0) * H + n], NLOG2E * W2[(16 + j1) * H + n]);
        // dh1: A[h1=n][k=h2], W3 pre-folded
        A_dh1a.i[t] = cvt_pk_bf16(W2[n * H + j0] * W3[j0],           W2[n * H + j1] * W3[j1]);
        A_dh1b.i[t] = cvt_pk_bf16(W2[n * H + 16 + j0] * W3[16 + j0], W2[n * H + 16 + j1] * W3[16 + j1]);
        // dy: A[c=n][k=h1], rows >= 2 zero
        A_dya.i[t] = (n < 2) ? cvt_pk_bf16(W1[n * H + j0],      W1[n * H + j1])      : 0;
        A_dyb.i[t] = (n < 2) ? cvt_pk_bf16(W1[n * H + 16 + j0], W1[n * H + 16 + j1]) : 0;
    }

    // z1 A-frag: k-slots (q5==0 half): {whi0,whi1, wlo0,wlo1, whi0,whi1, b1hi,b1lo}
    // pairing with B = {y1hi,y2hi, y1hi,y2hi, y1lo,y2lo, 1,1}; q5==1 half all zero.
    A_z1.i[0] = A_z1.i[1] = A_z1.i[2] = A_z1.i[3] = 0;
    if (q5 == 0) {
        const float wa = NLOG2E * W1[n];
        const float wb = NLOG2E * W1[H + n];
        const float bv = NLOG2E * b1[n];
        const int hi  = cvt_pk_bf16(wa, wb);
        const int lo  = cvt_pk_bf16(wa - pklo(hi), wb - pkhi(hi));
        const int bh  = cvt_pk_bf16(bv, 0.f);
        const int bhl = cvt_pk_bf16(bv, bv - pklo(bh));
        A_z1.i[0] = hi; A_z1.i[1] = lo; A_z1.i[2] = hi; A_z1.i[3] = bhl;
    }

    // acc init for z2: -log2e*b2 at rows h2 = (r&3)+8*(r>>2)+4*q5
    f32x16 b2C;
    #pragma unroll
    for (int t = 0; t < 4; ++t) {
        const float4 bt = *(const float4*)&b2[8 * t + 4 * q5];
        b2C[4 * t + 0] = NLOG2E * bt.x; b2C[4 * t + 1] = NLOG2E * bt.y;
        b2C[4 * t + 2] = NLOG2E * bt.z; b2C[4 * t + 3] = NLOG2E * bt.w;
    }

    f32x16 zf16;
    #pragma unroll
    for (int r = 0; r < 16; ++r) zf16[r] = 0.f;

    const int gwave  = (blockIdx.x * blockDim.x + tid) >> 6;
    const int nwaves = (gridDim.x * blockDim.x) >> 6;
    unsigned idx = (unsigned)gwave * 32 + (unsigned)n;   // lanes 0-31 load/store
    const unsigned step = (unsigned)nwaves * 32;

    for (int tt = gwave; tt < ntiles; tt += nwaves) {
        float y1v = 0.f, y2v = 0.f, xv1 = 0.f, xv2 = 0.f;
        if (lane < 32) {
            y1v = y1[idx]; y2v = y2[idx];
            xv1 = x1[idx]; xv2 = x2[idx];
        }

        // ---- B-frag for z1: y hi/lo split; upper-half A is zero (don't-care B) ----
        U4 uY;
        const int pkHI = cvt_pk_bf16(y1v, y2v);
        const int pkLO = cvt_pk_bf16(y1v - pklo(pkHI), y2v - pkhi(pkHI));
        uY.i[0] = pkHI; uY.i[1] = pkHI; uY.i[2] = pkLO;
        uY.i[3] = 0x3F803F80;   // (1.0,1.0) bias slots

        // ---- z1^T (scaled): one 32x32x16 MFMA ----
        const f32x16 acc = MFMA32(A_z1.v, uY.v, zf16, 0, 0, 0);

        // ---- sigmoid layer 1: 16 exp2 + 2 rcp (rcp8, pk product tree) -> P ----
        int P[8];
        #pragma unroll
        for (int h = 0; h < 2; ++h) {
            const int o = 8 * h;
            f32x2 A, Bv, Cv, Dv;
            A[0]  = __builtin_amdgcn_exp2f(acc[o + 0]);
            A[1]  = __builtin_amdgcn_exp2f(acc[o + 1]);
            Bv[0] = __builtin_amdgcn_exp2f(acc[o + 2]);
            Bv[1] = __builtin_amdgcn_exp2f(acc[o + 3]);
            Cv[0] = __builtin_amdgcn_exp2f(acc[o + 4]);
            Cv[1] = __builtin_amdgcn_exp2f(acc[o + 5]);
            Dv[0] = __builtin_amdgcn_exp2f(acc[o + 6]);
            Dv[1] = __builtin_amdgcn_exp2f(acc[o + 7]);
            A += 1.0f; Bv += 1.0f; Cv += 1.0f; Dv += 1.0f;        // v_pk_add_f32
            const f32x2 M1 = A * Bv, M2 = Cv * Dv, M = M1 * M2;   // v_pk_mul_f32
            const float r = __builtin_amdgcn_rcpf(M[0] * M[1]);   // prod8 <= 257^8, safe
            f32x2 R; R[0] = r * M[1]; R[1] = r * M[0];
            const f32x2 N1 = R * M2, N2 = R * M1;                 // (1/v0v2,1/v1v3),(1/v4v6,1/v5v7)
            const f32x2 S0 = Bv * N1, S1 = A * N1, S2 = Dv * N2, S3 = Cv * N2;
            P[4 * h + 0] = cvt_pk_bf16(S0[0], S0[1]);
            P[4 * h + 1] = cvt_pk_bf16(S1[0], S1[1]);
            P[4 * h + 2] = cvt_pk_bf16(S2[0], S2[1]);
            P[4 * h + 3] = cvt_pk_bf16(S3[0], S3[1]);
        }

        // ---- pivot h1 C->B via permlane32_swap (copies preserve P for h1d) ----
        U4 B1f, B2f;
        {
            int a0 = P[0], a2 = P[2]; plane32_swap(a0, a2);
            int a1 = P[1], a3 = P[3]; plane32_swap(a1, a3);
            B1f.i[0] = a0; B1f.i[1] = a1; B1f.i[2] = a2; B1f.i[3] = a3;
            int b0 = P[4], b2i = P[6]; plane32_swap(b0, b2i);
            int b1i = P[5], b3 = P[7]; plane32_swap(b1i, b3);
            B2f.i[0] = b0; B2f.i[1] = b1i; B2f.i[2] = b2i; B2f.i[3] = b3;
        }

        // ---- z2^T (scaled, b2 in acc init): K=32 via 2 chained MFMAs ----
        f32x16 zz = MFMA32(A_z2a.v, B1f.v, b2C, 0, 0, 0);
        zz = MFMA32(A_z2b.v, B2f.v, zz, 0, 0, 0);

        // ---- dz2 = s2*(1-s2): rcp8 sigmoid + pk_fma; write STRAIGHT into the
        //      B-frag unions, then swap in place (Q is dead — no copies) ----
        U4 D1f, D2f;
        #pragma unroll
        for (int h = 0; h < 2; ++h) {
            const int o = 8 * h;
            f32x2 A, Bv, Cv, Dv;
            A[0]  = __builtin_amdgcn_exp2f(zz[o + 0]);
            A[1]  = __builtin_amdgcn_exp2f(zz[o + 1]);
            Bv[0] = __builtin_amdgcn_exp2f(zz[o + 2]);
            Bv[1] = __builtin_amdgcn_exp2f(zz[o + 3]);
            Cv[0] = __builtin_amdgcn_exp2f(zz[o + 4]);
            Cv[1] = __builtin_amdgcn_exp2f(zz[o + 5]);
            Dv[0] = __builtin_amdgcn_exp2f(zz[o + 6]);
            Dv[1] = __builtin_amdgcn_exp2f(zz[o + 7]);
            A += 1.0f; Bv += 1.0f; Cv += 1.0f; Dv += 1.0f;
            const f32x2 M1 = A * Bv, M2 = Cv * Dv, M = M1 * M2;
            const float r = __builtin_amdgcn_rcpf(M[0] * M[1]);
            f32x2 R; R[0] = r * M[1]; R[1] = r * M[0];
            const f32x2 N1 = R * M2, N2 = R * M1;
            f32x2 S0 = Bv * N1, S1 = A * N1, S2 = Dv * N2, S3 = Cv * N2;
            S0 = __builtin_elementwise_fma(-S0, S0, S0);   // v_pk_fma_f32: s(1-s)
            S1 = __builtin_elementwise_fma(-S1, S1, S1);
            S2 = __builtin_elementwise_fma(-S2, S2, S2);
            S3 = __builtin_elementwise_fma(-S3, S3, S3);
            U4& Df = h ? D2f : D1f;
            Df.i[0] = cvt_pk_bf16(S0[0], S0[1]);
            Df.i[1] = cvt_pk_bf16(S1[0], S1[1]);
            Df.i[2] = cvt_pk_bf16(S2[0], S2[1]);
            Df.i[3] = cvt_pk_bf16(S3[0], S3[1]);
        }
        plane32_swap(D1f.i[0], D1f.i[2]);
        plane32_swap(D1f.i[1], D1f.i[3]);
        plane32_swap(D2f.i[0], D2f.i[2]);
        plane32_swap(D2f.i[1], D2f.i[3]);

        // ---- dH1^T = (W2*W3) @ dZ2^T ----
        f32x16 dh = MFMA32(A_dh1a.v, D1f.v, zf16, 0, 0, 0);
        dh = MFMA32(A_dh1b.v, D2f.v, dh, 0, 0, 0);

        // ---- dz1 = dH1 * h1d (h1d from packed bf16 s); straight into E, swap in place
        U4 E1f, E2f;
        #pragma unroll
        for (int t = 0; t < 4; ++t) {
            U4& Ef = (t & 2) ? E2f : E1f;
            const int sl = 2 * (t & 1);
            f32x2 sv, gg;
            sv[0] = pklo(P[2 * t]); sv[1] = pkhi(P[2 * t]);
            sv = __builtin_elementwise_fma(-sv, sv, sv);
            gg[0] = dh[4 * t]; gg[1] = dh[4 * t + 1]; gg *= sv;
            Ef.i[sl] = cvt_pk_bf16(gg[0], gg[1]);
            sv[0] = pklo(P[2 * t + 1]); sv[1] = pkhi(P[2 * t + 1]);
            sv = __builtin_elementwise_fma(-sv, sv, sv);
            gg[0] = dh[4 * t + 2]; gg[1] = dh[4 * t + 3]; gg *= sv;
            Ef.i[sl + 1] = cvt_pk_bf16(gg[0], gg[1]);
        }
        plane32_swap(E1f.i[0], E1f.i[2]);
        plane32_swap(E1f.i[1], E1f.i[3]);
        plane32_swap(E2f.i[0], E2f.i[2]);
        plane32_swap(E2f.i[1], E2f.i[3]);

        // ---- dY^T = W1 @ dZ1^T: lanes 0-31 hold g1=reg0, g2=reg1 ----
        f32x16 ay = MFMA32(A_dya.v, E1f.v, zf16, 0, 0, 0);
        ay = MFMA32(A_dyb.v, E2f.v, ay, 0, 0, 0);

        if (lane < 32) {
            float4 o;
            o.x = xv1 + ay[0];
            o.y = xv2 + ay[1];
            o.z = y1v;
            o.w = y2v;
            out[idx] = o;
        }

        idx += step;
    }
}

extern "C" void kernel_launch(void* const* d_in, const int* in_sizes, int n_in,
                              void* d_out, int out_size, void* d_ws, size_t ws_size,
                              hipStream_t stream) {
    const float* x1 = (const float*)d_in[0];
    const float* x2 = (const float*)d_in[1];
    const float* y1 = (const float*)d_in[2];
    const float* y2 = (const float*)d_in[3];
    const float* W1 = (const float*)d_in[4];
    const float* b1 = (const float*)d_in[5];
    const float* W2 = (const float*)d_in[6];
    const float* b2 = (const float*)d_in[7];
    const float* W3 = (const float*)d_in[8];
    // d_in[9] = b3: drops out of the input-gradient — unused.

    const int n = in_sizes[0];
    const int ntiles = n / 32;       // B = 4194304 -> 131072 tiles of 32
    const int block = 256;           // 4 waves
    const int grid = 1536;           // 6 blocks/CU (no-spill cap incl. accums)
    tinymlp_mfma_kernel<<<grid, block, 0, stream>>>(
        x1, x2, y1, y2, W1, b1, W2, b2, W3, (float4*)d_out, ntiles);
}

// Round 13
// 190.421 us; speedup vs baseline: 1.1724x; 1.0955x over previous
//
#include <hip/hip_runtime.h>

// TinyMLP (2 -> 32 -> 32 -> 1, sigmoid) analytic input-gradient, fused, MFMA-based.
// R13: TWO-TILE INTERLEAVE on the barrier-free R12 body, 4 waves/SIMD (cap 128).
// Evidence: R12 cut VALU demand 13% and wall stayed flat (idle absorbed it) ->
// not issue-bound on any pipe (VALU 49%, trans ~27%, MFMA 11%, HBM 13%). Per-wave
// tile latency ~12.9Kcy vs ~1.3Kcy issue -> 90% stalled; register file pins waves
// at 6/SIMD. Lever: MORE INDEPENDENT CHAINS PER WAVE. Unlike R2's failed pairing
// (4 wave-barriers locked tiles into lockstep), this body has ZERO barriers —
// tiles A (idx) and B (idx+32) interleave freely in the scheduler.
// Trade: TLP 6->4 waves (x0.67) for chain-ILP x2 -> 8 effective contexts vs 6.
// Register budget: ~72 true (R12) + ~36 second-tile transients = ~110 < 128 cap.
// Spill tell (R4/R7/R8/R10): VGPR_Count drop + FETCH/WRITE balloon -> revert.
//
// Pivot-by-swap (verified-by-run R9/R12): lane n / n+32 jointly hold all 32 rows
// of batch col n; v_permlane32_swap_b32 d,s -> d'=[d.lo|s.lo], s'=[d.hi|s.hi].
//   MFMA z1  (x1): -log2e*Z1^T = A_z1 @ Y^T    (y hi/lo bf16 split, b1 in K-slots 6,7)
//   MFMA z2  (x2): -log2e*Z2^T = W2s @ H1^T    (K=32; acc init = -log2e*b2)
//   MFMA dh1 (x2): dH1^T = (W2*W3) @ dZ2^T     (W3 folded into weights at init)
//   MFMA dy  (x2): dY^T  = W1 @ dZ1^T          (g1,g2 = regs 0,1 of lanes 0-31)
// rcp8 sigmoid (verified R12): one v_rcp per 8 denominators, pk product tree.
//
// Layouts (32x32x16 bf16; verified-by-run R5/R9):
//   A-frag: lane holds A[row=lane&31][k=(lane>>5)*8+j]
//   B-frag: lane holds B[k=(lane>>5)*8+j][n=lane&31]
//   C/D:    lane holds D[row=(reg&3)+8*(reg>>2)+4*(lane>>5)][col=lane&31]

#define H 32
#define NLOG2E (-1.4426950408889634f)

typedef __attribute__((ext_vector_type(8))) short bf16x8;
typedef __attribute__((ext_vector_type(16))) float f32x16;
typedef __attribute__((ext_vector_type(2))) float f32x2;
typedef __attribute__((ext_vector_type(2))) __bf16 bfx2;

#define MFMA32 __builtin_amdgcn_mfma_f32_32x32x16_bf16

__device__ __forceinline__ int cvt_pk_bf16(float a, float b) {
    f32x2 f; f[0] = a; f[1] = b;
    bfx2 r = __builtin_convertvector(f, bfx2);   // v_cvt_pk_bf16_f32 (RNE)
    return __builtin_bit_cast(int, r);
}
__device__ __forceinline__ float pklo(int p) {               // low bf16 of packed pair
    unsigned u = (unsigned)p << 16; return __builtin_bit_cast(float, u);
}
__device__ __forceinline__ float pkhi(int p) {               // high bf16 of packed pair
    unsigned u = (unsigned)p & 0xFFFF0000u; return __builtin_bit_cast(float, u);
}

// d.hi <-> s.lo (gfx950): after the asm, d = [d.lo|s.lo], s = [d.hi|s.hi].
__device__ __forceinline__ void plane32_swap(int &d, int &s) {
    asm volatile("v_permlane32_swap_b32 %0, %1" : "+v"(d), "+v"(s));
}

__global__ __launch_bounds__(256, 4) void tinymlp_mfma_kernel(
    const float* __restrict__ x1, const float* __restrict__ x2,
    const float* __restrict__ y1, const float* __restrict__ y2,
    const float* __restrict__ W1, const float* __restrict__ b1,
    const float* __restrict__ W2, const float* __restrict__ b2,
    const float* __restrict__ W3,
    float4* __restrict__ out, int ntiles)
{
    const int tid  = threadIdx.x;
    const int lane = tid & 63;
    const int n    = lane & 31;   // batch column (and weight row for A-frags)
    const int q5   = lane >> 5;   // k-half / h-half selector

    union U4 { int i[4]; bf16x8 v; };
    U4 A_z1, A_z2a, A_z2b, A_dh1a, A_dh1b, A_dya, A_dyb;

    #pragma unroll
    for (int t = 0; t < 4; ++t) {
        const int j0 = 8 * q5 + 2 * t;
        const int j1 = j0 + 1;
        // z2: A[h2=n][k=h1], forward scale folded
        A_z2a.i[t] = cvt_pk_bf16(NLOG2E * W2[j0 * H + n],        NLOG2E * W2[j1 * H + n]);
        A_z2b.i[t] = cvt_pk_bf16(NLOG2E * W2[(16 + j0) * H + n], NLOG2E * W2[(16 + j1) * H + n]);
        // dh1: A[h1=n][k=h2], W3 pre-folded
        A_dh1a.i[t] = cvt_pk_bf16(W2[n * H + j0] * W3[j0],           W2[n * H + j1] * W3[j1]);
        A_dh1b.i[t] = cvt_pk_bf16(W2[n * H + 16 + j0] * W3[16 + j0], W2[n * H + 16 + j1] * W3[16 + j1]);
        // dy: A[c=n][k=h1], rows >= 2 zero
        A_dya.i[t] = (n < 2) ? cvt_pk_bf16(W1[n * H + j0],      W1[n * H + j1])      : 0;
        A_dyb.i[t] = (n < 2) ? cvt_pk_bf16(W1[n * H + 16 + j0], W1[n * H + 16 + j1]) : 0;
    }

    // z1 A-frag: k-slots (q5==0 half): {whi0,whi1, wlo0,wlo1, whi0,whi1, b1hi,b1lo}
    // pairing with B = {y1hi,y2hi, y1hi,y2hi, y1lo,y2lo, 1,1}; q5==1 half all zero.
    A_z1.i[0] = A_z1.i[1] = A_z1.i[2] = A_z1.i[3] = 0;
    if (q5 == 0) {
        const float wa = NLOG2E * W1[n];
        const float wb = NLOG2E * W1[H + n];
        const float bv = NLOG2E * b1[n];
        const int hi  = cvt_pk_bf16(wa, wb);
        const int lo  = cvt_pk_bf16(wa - pklo(hi), wb - pkhi(hi));
        const int bh  = cvt_pk_bf16(bv, 0.f);
        const int bhl = cvt_pk_bf16(bv, bv - pklo(bh));
        A_z1.i[0] = hi; A_z1.i[1] = lo; A_z1.i[2] = hi; A_z1.i[3] = bhl;
    }

    // acc init for z2: -log2e*b2 at rows h2 = (r&3)+8*(r>>2)+4*q5
    f32x16 b2C;
    #pragma unroll
    for (int t = 0; t < 4; ++t) {
        const float4 bt = *(const float4*)&b2[8 * t + 4 * q5];
        b2C[4 * t + 0] = NLOG2E * bt.x; b2C[4 * t + 1] = NLOG2E * bt.y;
        b2C[4 * t + 2] = NLOG2E * bt.z; b2C[4 * t + 3] = NLOG2E * bt.w;
    }

    f32x16 zf16;
    #pragma unroll
    for (int r = 0; r < 16; ++r) zf16[r] = 0.f;

    // ---- per-stage helpers (constant-indexed arrays only; called once per tile) ----
    auto mkY = [&](float a, float b, U4& u) {
        const int hi = cvt_pk_bf16(a, b);
        const int lo = cvt_pk_bf16(a - pklo(hi), b - pkhi(hi));
        u.i[0] = hi; u.i[1] = hi; u.i[2] = lo; u.i[3] = 0x3F803F80;
    };
    // sigmoid of -log2e-scaled z: 16 exp2 + 2 rcp (rcp8 pk tree) -> packed bf16 P[8]
    auto sig8 = [&](const f32x16& z, int* P) {
        #pragma unroll
        for (int h = 0; h < 2; ++h) {
            const int o = 8 * h;
            f32x2 A, Bv, Cv, Dv;
            A[0]  = __builtin_amdgcn_exp2f(z[o + 0]);
            A[1]  = __builtin_amdgcn_exp2f(z[o + 1]);
            Bv[0] = __builtin_amdgcn_exp2f(z[o + 2]);
            Bv[1] = __builtin_amdgcn_exp2f(z[o + 3]);
            Cv[0] = __builtin_amdgcn_exp2f(z[o + 4]);
            Cv[1] = __builtin_amdgcn_exp2f(z[o + 5]);
            Dv[0] = __builtin_amdgcn_exp2f(z[o + 6]);
            Dv[1] = __builtin_amdgcn_exp2f(z[o + 7]);
            A += 1.0f; Bv += 1.0f; Cv += 1.0f; Dv += 1.0f;        // v_pk_add_f32
            const f32x2 M1 = A * Bv, M2 = Cv * Dv, M = M1 * M2;   // v_pk_mul_f32
            const float r = __builtin_amdgcn_rcpf(M[0] * M[1]);   // prod8 <= 257^8
            f32x2 R; R[0] = r * M[1]; R[1] = r * M[0];
            const f32x2 N1 = R * M2, N2 = R * M1;
            const f32x2 S0 = Bv * N1, S1 = A * N1, S2 = Dv * N2, S3 = Cv * N2;
            P[4 * h + 0] = cvt_pk_bf16(S0[0], S0[1]);
            P[4 * h + 1] = cvt_pk_bf16(S1[0], S1[1]);
            P[4 * h + 2] = cvt_pk_bf16(S2[0], S2[1]);
            P[4 * h + 3] = cvt_pk_bf16(S3[0], S3[1]);
        }
    };
    // pivot packed C-ints -> two B-frags, preserving P (copies then swap)
    auto pivP = [&](const int* P, U4& F1, U4& F2) {
        int a0 = P[0], a2 = P[2]; plane32_swap(a0, a2);
        int a1 = P[1], a3 = P[3]; plane32_swap(a1, a3);
        F1.i[0] = a0; F1.i[1] = a1; F1.i[2] = a2; F1.i[3] = a3;
        int b0 = P[4], b2i = P[6]; plane32_swap(b0, b2i);
        int b1i = P[5], b3 = P[7]; plane32_swap(b1i, b3);
        F2.i[0] = b0; F2.i[1] = b1i; F2.i[2] = b2i; F2.i[3] = b3;
    };
    // dz2 = s2(1-s2) straight into B-frag unions, swap in place
    auto dz2f = [&](const f32x16& zz, U4& D1, U4& D2) {
        #pragma unroll
        for (int h = 0; h < 2; ++h) {
            const int o = 8 * h;
            f32x2 A, Bv, Cv, Dv;
            A[0]  = __builtin_amdgcn_exp2f(zz[o + 0]);
            A[1]  = __builtin_amdgcn_exp2f(zz[o + 1]);
            Bv[0] = __builtin_amdgcn_exp2f(zz[o + 2]);
            Bv[1] = __builtin_amdgcn_exp2f(zz[o + 3]);
            Cv[0] = __builtin_amdgcn_exp2f(zz[o + 4]);
            Cv[1] = __builtin_amdgcn_exp2f(zz[o + 5]);
            Dv[0] = __builtin_amdgcn_exp2f(zz[o + 6]);
            Dv[1] = __builtin_amdgcn_exp2f(zz[o + 7]);
            A += 1.0f; Bv += 1.0f; Cv += 1.0f; Dv += 1.0f;
            const f32x2 M1 = A * Bv, M2 = Cv * Dv, M = M1 * M2;
            const float r = __builtin_amdgcn_rcpf(M[0] * M[1]);
            f32x2 R; R[0] = r * M[1]; R[1] = r * M[0];
            const f32x2 N1 = R * M2, N2 = R * M1;
            f32x2 S0 = Bv * N1, S1 = A * N1, S2 = Dv * N2, S3 = Cv * N2;
            S0 = __builtin_elementwise_fma(-S0, S0, S0);
            S1 = __builtin_elementwise_fma(-S1, S1, S1);
            S2 = __builtin_elementwise_fma(-S2, S2, S2);
            S3 = __builtin_elementwise_fma(-S3, S3, S3);
            U4& Df = h ? D2 : D1;
            Df.i[0] = cvt_pk_bf16(S0[0], S0[1]);
            Df.i[1] = cvt_pk_bf16(S1[0], S1[1]);
            Df.i[2] = cvt_pk_bf16(S2[0], S2[1]);
            Df.i[3] = cvt_pk_bf16(S3[0], S3[1]);
        }
        plane32_swap(D1.i[0], D1.i[2]);
        plane32_swap(D1.i[1], D1.i[3]);
        plane32_swap(D2.i[0], D2.i[2]);
        plane32_swap(D2.i[1], D2.i[3]);
    };
    // dz1 = dH1 * h1d straight into B-frag unions, swap in place
    auto dz1f = [&](const f32x16& dh, const int* P, U4& E1, U4& E2) {
        #pragma unroll
        for (int t = 0; t < 4; ++t) {
            U4& Ef = (t & 2) ? E2 : E1;
            const int sl = 2 * (t & 1);
            f32x2 sv, gg;
            sv[0] = pklo(P[2 * t]); sv[1] = pkhi(P[2 * t]);
            sv = __builtin_elementwise_fma(-sv, sv, sv);
            gg[0] = dh[4 * t]; gg[1] = dh[4 * t + 1]; gg *= sv;
            Ef.i[sl] = cvt_pk_bf16(gg[0], gg[1]);
            sv[0] = pklo(P[2 * t + 1]); sv[1] = pkhi(P[2 * t + 1]);
            sv = __builtin_elementwise_fma(-sv, sv, sv);
            gg[0] = dh[4 * t + 2]; gg[1] = dh[4 * t + 3]; gg *= sv;
            Ef.i[sl + 1] = cvt_pk_bf16(gg[0], gg[1]);
        }
        plane32_swap(E1.i[0], E1.i[2]);
        plane32_swap(E1.i[1], E1.i[3]);
        plane32_swap(E2.i[0], E2.i[2]);
        plane32_swap(E2.i[1], E2.i[3]);
    };

    const int gpair  = (blockIdx.x * blockDim.x + tid) >> 6;
    const int nwaves = (gridDim.x * blockDim.x) >> 6;
    const int npairs = ntiles >> 1;
    unsigned idx = (unsigned)gpair * 64 + (unsigned)n;   // tile A elem; B = idx+32
    const unsigned step = (unsigned)nwaves * 64;

    for (int pp = gpair; pp < npairs; pp += nwaves) {
        float yA1 = 0.f, yA2 = 0.f, xA1 = 0.f, xA2 = 0.f;
        float yB1 = 0.f, yB2 = 0.f, xB1 = 0.f, xB2 = 0.f;
        if (lane < 32) {
            yA1 = y1[idx];      yA2 = y2[idx];
            yB1 = y1[idx + 32]; yB2 = y2[idx + 32];
            xA1 = x1[idx];      xA2 = x2[idx];
            xB1 = x1[idx + 32]; xB2 = x2[idx + 32];
        }

        // ---- stage-interleaved A/B: zero barriers -> two independent chains ----
        U4 uYA, uYB;
        mkY(yA1, yA2, uYA);
        mkY(yB1, yB2, uYB);
        const f32x16 accA = MFMA32(A_z1.v, uYA.v, zf16, 0, 0, 0);
        const f32x16 accB = MFMA32(A_z1.v, uYB.v, zf16, 0, 0, 0);

        int PA[8], PB[8];
        sig8(accA, PA);
        sig8(accB, PB);

        U4 B1A, B2A, B1B, B2B;
        pivP(PA, B1A, B2A);
        pivP(PB, B1B, B2B);

        f32x16 zzA = MFMA32(A_z2a.v, B1A.v, b2C, 0, 0, 0);
        f32x16 zzB = MFMA32(A_z2a.v, B1B.v, b2C, 0, 0, 0);
        zzA = MFMA32(A_z2b.v, B2A.v, zzA, 0, 0, 0);
        zzB = MFMA32(A_z2b.v, B2B.v, zzB, 0, 0, 0);

        U4 D1A, D2A, D1B, D2B;
        dz2f(zzA, D1A, D2A);
        dz2f(zzB, D1B, D2B);

        f32x16 dhA = MFMA32(A_dh1a.v, D1A.v, zf16, 0, 0, 0);
        f32x16 dhB = MFMA32(A_dh1a.v, D1B.v, zf16, 0, 0, 0);
        dhA = MFMA32(A_dh1b.v, D2A.v, dhA, 0, 0, 0);
        dhB = MFMA32(A_dh1b.v, D2B.v, dhB, 0, 0, 0);

        U4 E1A, E2A, E1B, E2B;
        dz1f(dhA, PA, E1A, E2A);
        dz1f(dhB, PB, E1B, E2B);

        f32x16 ayA = MFMA32(A_dya.v, E1A.v, zf16, 0, 0, 0);
        f32x16 ayB = MFMA32(A_dya.v, E1B.v, zf16, 0, 0, 0);
        ayA = MFMA32(A_dyb.v, E2A.v, ayA, 0, 0, 0);
        ayB = MFMA32(A_dyb.v, E2B.v, ayB, 0, 0, 0);

        if (lane < 32) {
            float4 oA;
            oA.x = xA1 + ayA[0];
            oA.y = xA2 + ayA[1];
            oA.z = yA1;
            oA.w = yA2;
            out[idx] = oA;
            float4 oB;
            oB.x = xB1 + ayB[0];
            oB.y = xB2 + ayB[1];
            oB.z = yB1;
            oB.w = yB2;
            out[idx + 32] = oB;
        }

        idx += step;
    }
}

extern "C" void kernel_launch(void* const* d_in, const int* in_sizes, int n_in,
                              void* d_out, int out_size, void* d_ws, size_t ws_size,
                              hipStream_t stream) {
    const float* x1 = (const float*)d_in[0];
    const float* x2 = (const float*)d_in[1];
    const float* y1 = (const float*)d_in[2];
    const float* y2 = (const float*)d_in[3];
    const float* W1 = (const float*)d_in[4];
    const float* b1 = (const float*)d_in[5];
    const float* W2 = (const float*)d_in[6];
    const float* b2 = (const float*)d_in[7];
    const float* W3 = (const float*)d_in[8];
    // d_in[9] = b3: drops out of the input-gradient — unused.

    const int n = in_sizes[0];
    const int ntiles = n / 32;       // B = 4194304 -> 131072 tiles of 32 (65536 pairs)
    const int block = 256;           // 4 waves
    const int grid = 1024;           // 4 blocks/CU -> 4 waves/SIMD, VGPR cap 128
    tinymlp_mfma_kernel<<<grid, block, 0, stream>>>(
        x1, x2, y1, y2, W1, b1, W2, b2, W3, (float4*)d_out, ntiles);
}